// Round 3
// baseline (2677.983 us; speedup 1.0000x reference)
//
#include <hip/hip_runtime.h>
#include <hip/hip_fp16.h>
#include <cmath>

// Problem constants (reference: B=256, T=512, IN=64, R=2048)
constexpr int kB  = 256;
constexpr int kT  = 512;
constexpr int kIN = 64;
constexpr int kR  = 2048;

constexpr int kBands  = 8;             // m-bands; band = blockIdx&7 -> XCD-local under
                                       // round-robin dispatch (r9/r12-verified)
constexpr int kNB     = 32;            // n-blocks per band
constexpr int kBlocks = kBands * kNB;  // 256 -> 1 block/CU (r10: 2/CU regresses)
constexpr int BM = 32;                 // batches per block
constexpr int BN = 64;                 // n per block (W-band in registers)
constexpr int PFS = 68;                // partial-scratch row stride (words)

typedef _Float16 f16x8 __attribute__((ext_vector_type(8)));
typedef float    f32x4 __attribute__((ext_vector_type(4)));
typedef unsigned long long u64;

#define MFMA16(a, b, c) __builtin_amdgcn_mfma_f32_16x16x32_f16((a), (b), (c), 0, 0, 0)

__device__ __forceinline__ f16x8 cvt8(float4 a, float4 b) {
    f16x8 v;
    v[0] = (_Float16)a.x; v[1] = (_Float16)a.y; v[2] = (_Float16)a.z; v[3] = (_Float16)a.w;
    v[4] = (_Float16)b.x; v[5] = (_Float16)b.y; v[6] = (_Float16)b.z; v[7] = (_Float16)b.w;
    return v;
}

__device__ __forceinline__ unsigned get_xcc_id() {
    unsigned x;
    asm volatile("s_getreg_b32 %0, hwreg(HW_REG_XCC_ID, 0, 8)" : "=s"(x));
    return x & 0xfu;
}

// Fast tanh: 1 - 2/(e^{2x}+1) via hw v_exp_f32. Saturates exactly to +/-1 for
// large |x|; ~1e-6 abs error — negligible vs the 9.8e-3 f16-path absmax.
__device__ __forceinline__ float fast_tanh(float x) {
    float e = __expf(2.0f * x);
    return 1.0f - 2.0f / (e + 1.0f);
}

// One coalesced poll of the band's 32 per-block flags (agent-scope).
__device__ __forceinline__ unsigned poll32(const unsigned* f, int lane, unsigned target) {
    unsigned v = __hip_atomic_load(f + (lane & 31), __ATOMIC_RELAXED, __HIP_MEMORY_SCOPE_AGENT);
    return (unsigned)__ballot(v >= target);
}

// Persistent ESN, r20 = r17 producer/epilogue/publish (r19's counter-publish
// and pf-dbuf REVERTED: +5%, publish path was already minimal) + consumer-side
// partial-start:
//   - ONE global poller (wave0, r18 lesson: poll fan-out regresses). Each poll
//     iteration wave0 publishes the running ready-ballot to an LDS word;
//     waves 1..7 spin LOCALLY on LDS (no L2 traffic) and proceed as soon as
//     THEIR 4 producers (nb' = 4q..4q+3) are ready — straggler wait overlaps
//     the early waves' L2 fragment streams. Barrier 1 deleted on fast path.
//   - Fragment loads are agent-scope relaxed atomic loads (sc0, L1-bypass):
//     same L2 latency the post-buffer_inv loads had, but no inv instruction
//     and per-wave-start-safe. r12's coherence argument carries over with
//     L1-bypass replacing L1-inv (CDNA L1 is write-through; flag-in-L2 implies
//     data-in-L2 via producer's s_waitcnt-before-publish).
//   - Hazard audit: pf write(t) ordered after pf reads(t-1) by B3(t-1) (all
//     waves pass it). s-overwrite(t over t-2) guarded because B2(t) joins all
//     8 waves whose gate union = all 32 flags >= t — identical to r17.
//   - mask word is 32-bit (no tearing), per t-parity; reset by tid0 in the
//     B2->B3 window of the previous step (barrier-ordered both sides).
//   - Input-term MFMAs hoisted before the gate: flag-independent work now
//     runs in the wait shadow.
//   t==1 (and any non-co-located band, fast_sh==0) keeps the r17 centralized
//   safe path verbatim: wave0 poll + agent-acquire fence + full barrier +
//   plain loads.
__global__ __launch_bounds__(512, 2) void esn_persist(
    const float* __restrict__ X,     // [B, T, IN]
    const float* __restrict__ Win,   // [R, IN]
    const float* __restrict__ W,     // [R, R]
    float* __restrict__ out,         // [B, R]
    _Float16* __restrict__ sbuf0,    // swizzled, 1 MB
    _Float16* __restrict__ sbuf1,    // swizzled, 1 MB
    unsigned* __restrict__ flags,    // [8][32], zeroed at launch
    unsigned* __restrict__ xcds)     // [8][32], zeroed at launch
{
    __shared__ __align__(16) float pf[8 * BM * PFS];     // 69632 B
    __shared__ int fast_sh;
    __shared__ unsigned mask2[2];    // per-parity ready-ballot relay (LDS)

    const int tid  = threadIdx.x;
    const int wave = tid >> 6, lane = tid & 63;
    const int quad = lane >> 4, l16 = lane & 15;
    const int q  = wave;             // k-phase: k-slab [256q, 256q+256)
    const int mb = blockIdx.x & 7;   // band (XCD-local heuristic, HW-verified)
    const int nb = blockIdx.x >> 3;  // n-block within band
    const int n0 = nb * BN;
    const int m0 = mb * BM;
    unsigned* bandflags = flags + mb * kNB;
    unsigned* bandxcc   = xcds  + mb * kNB;

    if (tid == 0) {
        fast_sh = 0;
        mask2[0] = 0; mask2[1] = 0;
        __hip_atomic_store(&bandxcc[nb], get_xcc_id() + 1u,
                           __ATOMIC_RELAXED, __HIP_MEMORY_SCOPE_AGENT);
    }

    // ---- one-time: W-band -> register B-frags (f16) ----
    // wfrag[nt][j] = W[n0+nt*16+l16][kk*32+quad*8+..], kk = 8q+j, j=0..7
    f16x8 wfrag[4][8];
    #pragma unroll
    for (int nt = 0; nt < 4; ++nt) {
        const float* wrow = W + (size_t)(n0 + nt * 16 + l16) * kR;
        #pragma unroll
        for (int j = 0; j < 8; ++j) {
            const float* p = wrow + (8 * q + j) * 32 + quad * 8;
            wfrag[nt][j] = cvt8(*(const float4*)p, *(const float4*)(p + 4));
        }
    }
    // input term: K=64 = 2 k-windows; waves q=0,1 own window q
    f16x8 winfrag[4] = {};
    if (q < 2) {
        #pragma unroll
        for (int nt = 0; nt < 4; ++nt) {
            const float* p = Win + (size_t)(n0 + nt * 16 + l16) * kIN
                           + q * 32 + quad * 8;
            winfrag[nt] = cvt8(*(const float4*)p, *(const float4*)(p + 4));
        }
    }

    // Consumer fragment geometry (swizzled layout, r15-verified):
    // frag (mt, j) at halfs offset fbase + mt*32768 + j*512, kw = 8q+j.
    const size_t fbase = ((size_t)(mb * 2) * 64 + 8 * q) * 512 + quad * 128 + l16 * 8;

    // Per-wave producer-dependency bits: wave q's kw=8q+j come from
    // producers nb' = (8q+j)>>1 = 4q..4q+3 -> ballot bits 4q..4q+3.
    const unsigned req = 0xFu << (4 * q);

    // Producer epilogue geometry (r15-verified): 4 contiguous 1-KB runs.
    const int r_   = tid >> 7;            // run 0..3
    const int pos  = (tid & 127) * 4;     // halfs within run
    const int mt_w = r_ >> 1, kwl = r_ & 1;
    const int l16w = (pos >> 3) & 15, qw = pos >> 7, jw = pos & 7;
    const int m_loc = mt_w * 16 + l16w;                 // m within band
    const int nn    = kwl * 32 + qw * 8 + jw;           // n within block (0..63)
    const size_t soff = ((size_t)(mb * 2 + mt_w) * 64 + (nb * 2 + kwl)) * 512 + pos;

    #pragma unroll 1
    for (int t = 0; t < kT; ++t) {
        // ---- X-frag raw loads for THIS step (latency hidden under sync) ----
        float4 xr[2][2];
        if (q < 2) {
            #pragma unroll
            for (int i = 0; i < 2; ++i) {
                const float* xp = X + ((size_t)(m0 + i * 16 + l16) * kT + t) * kIN
                                + q * 32 + quad * 8;
                xr[i][0] = *(const float4*)xp;
                xr[i][1] = *(const float4*)(xp + 4);
            }
        }

        f32x4 acc[2][4] = {};   // [m-tile][n-tile]

        // ---- input term FIRST: flag-independent, runs in the wait shadow ----
        if (q < 2) {
            #pragma unroll
            for (int i = 0; i < 2; ++i) {
                f16x8 a = cvt8(xr[i][0], xr[i][1]);
                #pragma unroll
                for (int nt = 0; nt < 4; ++nt)
                    acc[i][nt] = MFMA16(a, winfrag[nt], acc[i][nt]);
            }
        }

        // ---- recurrent term ----
        if (t > 0) {
            const _Float16* sprev = (t & 1) ? sbuf0 : sbuf1;
            const unsigned target = (unsigned)t;   // flag >= t <=> s[t-1] published
            const _Float16* fp = sprev + fbase;
            union uf { u64 u[2]; f16x8 v; };
            uf af[16];   // all 16 fragments: flat issue, max MLP

            const bool fast = (t >= 2) && (fast_sh != 0);   // block-uniform
            if (fast) {
                unsigned* mw = &mask2[t & 1];
                if (wave == 0) {
                    // sole global poller; relays partial readiness via LDS
                    unsigned fm = poll32(bandflags, lane, target);
                    if (lane == 0)
                        __hip_atomic_store(mw, fm, __ATOMIC_RELAXED,
                                           __HIP_MEMORY_SCOPE_WORKGROUP);
                    int spins = 0;
                    while (fm != 0xffffffffu) {
                        if (++spins > 16) __builtin_amdgcn_s_sleep(1);
                        fm = poll32(bandflags, lane, target);
                        if (lane == 0)
                            __hip_atomic_store(mw, fm, __ATOMIC_RELAXED,
                                               __HIP_MEMORY_SCOPE_WORKGROUP);
                    }
                } else {
                    // local LDS spin: proceed when MY 4 producers are ready
                    unsigned m;
                    int spins = 0;
                    do {
                        m = __hip_atomic_load(mw, __ATOMIC_RELAXED,
                                              __HIP_MEMORY_SCOPE_WORKGROUP);
                        if (++spins > 1024) __builtin_amdgcn_s_sleep(1);
                    } while ((m & req) != req);
                }
                asm volatile("" ::: "memory");
                // sc0 (L1-bypass) fragment loads: straight from the XCD L2
                #pragma unroll
                for (int j = 0; j < 8; ++j)
                    #pragma unroll
                    for (int i = 0; i < 2; ++i) {
                        u64* p = (u64*)(fp + (size_t)i * 32768 + (size_t)j * 512);
                        af[j * 2 + i].u[0] = __hip_atomic_load(p, __ATOMIC_RELAXED,
                                                               __HIP_MEMORY_SCOPE_AGENT);
                        af[j * 2 + i].u[1] = __hip_atomic_load(p + 1, __ATOMIC_RELAXED,
                                                               __HIP_MEMORY_SCOPE_AGENT);
                    }
            } else {
                // r17 centralized safe path (t==1, or non-co-located band)
                if (wave == 0) {
                    unsigned fm = poll32(bandflags, lane, target);
                    int spins = 0;
                    while (fm != 0xffffffffu) {
                        if (++spins > 16) __builtin_amdgcn_s_sleep(1);
                        fm = poll32(bandflags, lane, target);
                    }
                    if (t == 1) {
                        // one-time: verify XCD co-location (xcds visible: flag>=1)
                        const unsigned myx = get_xcc_id() + 1u;
                        unsigned px = __hip_atomic_load(bandxcc + (lane & 31),
                                                        __ATOMIC_RELAXED,
                                                        __HIP_MEMORY_SCOPE_AGENT);
                        unsigned fw = (__ballot(px == myx) == ~0ull) ? 1u : 0u;
                        if (lane == 0) fast_sh = (int)fw;
                    }
                    // safe: full agent acquire (L1+L2 invalidate)
                    __builtin_amdgcn_fence(__ATOMIC_ACQUIRE, "agent");
                }
                __syncthreads();                   // barrier 1 (safe path only)
                asm volatile("" ::: "memory");
                #pragma unroll
                for (int j = 0; j < 8; ++j)
                    #pragma unroll
                    for (int i = 0; i < 2; ++i)
                        af[j * 2 + i].v = *(const f16x8*)(fp + (size_t)i * 32768
                                                          + (size_t)j * 512);
            }

            #pragma unroll
            for (int j = 0; j < 8; ++j) {
                #pragma unroll
                for (int i = 0; i < 2; ++i) {
                    f16x8 av = af[j * 2 + i].v;
                    acc[i][0] = MFMA16(av, wfrag[0][j], acc[i][0]);
                    acc[i][1] = MFMA16(av, wfrag[1][j], acc[i][1]);
                    acc[i][2] = MFMA16(av, wfrag[2][j], acc[i][2]);
                    acc[i][3] = MFMA16(av, wfrag[3][j], acc[i][3]);
                }
            }
        }

        // ---- reduce 8 k-phase partials through LDS, tanh, swizzled store ----
        #pragma unroll
        for (int i = 0; i < 2; ++i)
            #pragma unroll
            for (int nt = 0; nt < 4; ++nt)
                #pragma unroll
                for (int r = 0; r < 4; ++r)
                    pf[q * BM * PFS + (i * 16 + quad * 4 + r) * PFS + nt * 16 + l16]
                        = acc[i][nt][r];
        __syncthreads();                           // barrier 2 (pf)
        // reset next step's mask parity word (ordered by B2 above, B3 below)
        if (tid == 0 && t < kT - 1) mask2[(t + 1) & 1] = 0;

        f32x4 vs = {};
        #pragma unroll
        for (int p = 0; p < 8; ++p) {
            f32x4 v = *(const f32x4*)&pf[p * BM * PFS + m_loc * PFS + nn];
            vs[0] += v[0]; vs[1] += v[1]; vs[2] += v[2]; vs[3] += v[3];
        }
        float o0 = fast_tanh(vs[0]);
        float o1 = fast_tanh(vs[1]);
        float o2 = fast_tanh(vs[2]);
        float o3 = fast_tanh(vs[3]);

        if (t < kT - 1) {
            _Float16* sout = (t & 1) ? sbuf1 : sbuf0;
            union { u64 u; _Float16 h[4]; } pk;
            pk.h[0] = (_Float16)o0; pk.h[1] = (_Float16)o1;
            pk.h[2] = (_Float16)o2; pk.h[3] = (_Float16)o3;
            u64* dst = (u64*)(sout + soff);        // contiguous across tids
            if (fast_sh) {
                *dst = pk.u;                     // write-back: lands in the
                asm volatile("" ::: "memory");   // XCD's shared L2 (verified)
            } else {
                __hip_atomic_store(dst, pk.u, __ATOMIC_RELAXED,
                                   __HIP_MEMORY_SCOPE_AGENT);  // through to L3
            }
            __builtin_amdgcn_s_waitcnt(0);   // store (and xcc publish) completed
            __syncthreads();                 // barrier 3 (drain; guards pf)
            if (tid == 0)
                __hip_atomic_store(&bandflags[nb], (unsigned)(t + 1),
                                   __ATOMIC_RELAXED, __HIP_MEMORY_SCOPE_AGENT);
        } else {
            // final step: write plain [B, R] fp32 output
            float4 o; o.x = o0; o.y = o1; o.z = o2; o.w = o3;
            *(float4*)(out + (size_t)(m0 + m_loc) * kR + n0 + nn) = o;
        }
    }
}

extern "C" void kernel_launch(void* const* d_in, const int* in_sizes, int n_in,
                              void* d_out, int out_size, void* d_ws, size_t ws_size,
                              hipStream_t stream)
{
    const float* X   = (const float*)d_in[0];  // [B, T, IN]
    const float* Win = (const float*)d_in[1];  // [R, IN]
    const float* W   = (const float*)d_in[2];  // [R, R]
    float* out = (float*)d_out;                // [B, R]

    char* ws = (char*)d_ws;
    _Float16* s0 = (_Float16*)ws;                                  // 1 MB (swizzled)
    _Float16* s1 = (_Float16*)(ws + (size_t)kB * kR * 2);          // 1 MB (swizzled)
    unsigned* flags = (unsigned*)(ws + 2 * (size_t)kB * kR * 2);   // [8][32]
    unsigned* xcds  = flags + kBands * kNB;                        // [8][32]

    hipMemsetAsync(flags, 0, 2 * kBands * kNB * sizeof(unsigned), stream);
    esn_persist<<<kBlocks, 512, 0, stream>>>(X, Win, W, out, s0, s1, flags, xcds);
}

// Round 5
// 2161.852 us; speedup vs baseline: 1.2387x; 1.2387x over previous
//
#include <hip/hip_runtime.h>
#include <hip/hip_fp16.h>
#include <cmath>

// Problem constants (reference: B=256, T=512, IN=64, R=2048)
constexpr int kB  = 256;
constexpr int kT  = 512;
constexpr int kIN = 64;
constexpr int kR  = 2048;

constexpr int kBands  = 8;             // m-bands; band = blockIdx&7 -> XCD-local under
                                       // round-robin dispatch (r9/r12-verified)
constexpr int kNB     = 32;            // n-blocks per band
constexpr int kBlocks = kBands * kNB;  // 256 -> 1 block/CU (r10: 2/CU regresses)
constexpr int BM = 32;                 // batches per block
constexpr int BN = 64;                 // n per block (W-band in registers)
constexpr int PFS = 68;                // partial-scratch row stride (words)

typedef _Float16 f16x8 __attribute__((ext_vector_type(8)));
typedef float    f32x4 __attribute__((ext_vector_type(4)));
typedef unsigned long long u64;

#define MFMA16(a, b, c) __builtin_amdgcn_mfma_f32_16x16x32_f16((a), (b), (c), 0, 0, 0)

__device__ __forceinline__ f16x8 cvt8(float4 a, float4 b) {
    f16x8 v;
    v[0] = (_Float16)a.x; v[1] = (_Float16)a.y; v[2] = (_Float16)a.z; v[3] = (_Float16)a.w;
    v[4] = (_Float16)b.x; v[5] = (_Float16)b.y; v[6] = (_Float16)b.z; v[7] = (_Float16)b.w;
    return v;
}

__device__ __forceinline__ unsigned get_xcc_id() {
    unsigned x;
    asm volatile("s_getreg_b32 %0, hwreg(HW_REG_XCC_ID, 0, 8)" : "=s"(x));
    return x & 0xfu;
}

// Fast tanh: 1 - 2/(e^{2x}+1) via hw v_exp_f32. Saturates exactly to +/-1 for
// large |x|; ~1e-6 abs error — negligible vs the 9.8e-3 f16-path absmax.
__device__ __forceinline__ float fast_tanh(float x) {
    float e = __expf(2.0f * x);
    return 1.0f - 2.0f / (e + 1.0f);
}

// One coalesced poll of the band's 32 per-block flags (agent-scope).
__device__ __forceinline__ unsigned poll32(const unsigned* f, int lane, unsigned target) {
    unsigned v = __hip_atomic_load(f + (lane & 31), __ATOMIC_RELAXED, __HIP_MEMORY_SCOPE_AGENT);
    return (unsigned)__ballot(v >= target);
}

// Persistent ESN, r21 = r17 + per-wave partial-start, load path UNCHANGED.
//   (resubmission: r21's bench never ran — GPU broker at capacity)
//   r20 post-mortem: the 46% regression was the load path (32x 8B atomic
//   bypass loads replacing 16x dwordx4), not the LDS-relay gating. r21 keeps
//   r17's plain f16x8 (dwordx4) fragment loads and r17's producer epilogue /
//   publish verbatim, and changes ONLY the consumer gate on the fast path:
//   - wave0: sole global poller (r18 lesson), relays its running ready-ballot
//     into an LDS word each poll iteration.
//   - waves 1..7: spin on the LDS word (zero L2 traffic) and proceed as soon
//     as THEIR 4 producers (nb' = 4q..4q+3) are ready; then a per-wave
//     buffer_inv sc0 (L1-wide inv after own-flag observation -> own fragment
//     lines refetch from L2; peer invs harmless, values land in registers).
//   - barrier 1 deleted on the fast path; straggler wait overlaps early
//     waves' 16-KB L2 streams + MFMA.
//   - input-term MFMAs hoisted before the gate (wait-shadow work).
//   Hazards: B2(t) still joins all 8 waves whose gate union = all 32 flags
//   >= t, so the s-overwrite and pf hazards keep r17's argument verbatim.
//   mask relay word is per-parity, reset by tid0 in the B2->B3 window two
//   steps ahead of its next use (barrier-ordered on both sides).
//   Safe path (t==1 or non-co-located band): r17 centralized path verbatim.
__global__ __launch_bounds__(512, 2) void esn_persist(
    const float* __restrict__ X,     // [B, T, IN]
    const float* __restrict__ Win,   // [R, IN]
    const float* __restrict__ W,     // [R, R]
    float* __restrict__ out,         // [B, R]
    _Float16* __restrict__ sbuf0,    // swizzled, 1 MB
    _Float16* __restrict__ sbuf1,    // swizzled, 1 MB
    unsigned* __restrict__ flags,    // [8][32], zeroed at launch
    unsigned* __restrict__ xcds)     // [8][32], zeroed at launch
{
    __shared__ __align__(16) float pf[8 * BM * PFS];     // 69632 B
    __shared__ int fast_sh;
    __shared__ unsigned mask2[2];    // per-parity ready-ballot relay (LDS)

    const int tid  = threadIdx.x;
    const int wave = tid >> 6, lane = tid & 63;
    const int quad = lane >> 4, l16 = lane & 15;
    const int q  = wave;             // k-phase: k-slab [256q, 256q+256)
    const int mb = blockIdx.x & 7;   // band (XCD-local heuristic, HW-verified)
    const int nb = blockIdx.x >> 3;  // n-block within band
    const int n0 = nb * BN;
    const int m0 = mb * BM;
    unsigned* bandflags = flags + mb * kNB;
    unsigned* bandxcc   = xcds  + mb * kNB;

    if (tid == 0) {
        fast_sh = 0;
        mask2[0] = 0; mask2[1] = 0;
        __hip_atomic_store(&bandxcc[nb], get_xcc_id() + 1u,
                           __ATOMIC_RELAXED, __HIP_MEMORY_SCOPE_AGENT);
    }

    // ---- one-time: W-band -> register B-frags (f16) ----
    // wfrag[nt][j] = W[n0+nt*16+l16][kk*32+quad*8+..], kk = 8q+j, j=0..7
    f16x8 wfrag[4][8];
    #pragma unroll
    for (int nt = 0; nt < 4; ++nt) {
        const float* wrow = W + (size_t)(n0 + nt * 16 + l16) * kR;
        #pragma unroll
        for (int j = 0; j < 8; ++j) {
            const float* p = wrow + (8 * q + j) * 32 + quad * 8;
            wfrag[nt][j] = cvt8(*(const float4*)p, *(const float4*)(p + 4));
        }
    }
    // input term: K=64 = 2 k-windows; waves q=0,1 own window q
    f16x8 winfrag[4] = {};
    if (q < 2) {
        #pragma unroll
        for (int nt = 0; nt < 4; ++nt) {
            const float* p = Win + (size_t)(n0 + nt * 16 + l16) * kIN
                           + q * 32 + quad * 8;
            winfrag[nt] = cvt8(*(const float4*)p, *(const float4*)(p + 4));
        }
    }

    // Consumer fragment geometry (swizzled layout, r15-verified):
    // frag (mt, j) at halfs offset fbase + mt*32768 + j*512, kw = 8q+j.
    const size_t fbase = ((size_t)(mb * 2) * 64 + 8 * q) * 512 + quad * 128 + l16 * 8;

    // Per-wave producer-dependency bits: wave q's kw=8q+j come from
    // producers nb' = (8q+j)>>1 = 4q..4q+3 -> ballot bits 4q..4q+3.
    const unsigned req = 0xFu << (4 * q);

    // Producer epilogue geometry (r15-verified): 4 contiguous 1-KB runs.
    const int r_   = tid >> 7;            // run 0..3
    const int pos  = (tid & 127) * 4;     // halfs within run
    const int mt_w = r_ >> 1, kwl = r_ & 1;
    const int l16w = (pos >> 3) & 15, qw = pos >> 7, jw = pos & 7;
    const int m_loc = mt_w * 16 + l16w;                 // m within band
    const int nn    = kwl * 32 + qw * 8 + jw;           // n within block (0..63)
    const size_t soff = ((size_t)(mb * 2 + mt_w) * 64 + (nb * 2 + kwl)) * 512 + pos;

    #pragma unroll 1
    for (int t = 0; t < kT; ++t) {
        // ---- X-frag raw loads for THIS step (latency hidden under sync) ----
        float4 xr[2][2];
        if (q < 2) {
            #pragma unroll
            for (int i = 0; i < 2; ++i) {
                const float* xp = X + ((size_t)(m0 + i * 16 + l16) * kT + t) * kIN
                                + q * 32 + quad * 8;
                xr[i][0] = *(const float4*)xp;
                xr[i][1] = *(const float4*)(xp + 4);
            }
        }

        f32x4 acc[2][4] = {};   // [m-tile][n-tile]

        // ---- input term FIRST: flag-independent, runs in the wait shadow ----
        if (q < 2) {
            #pragma unroll
            for (int i = 0; i < 2; ++i) {
                f16x8 a = cvt8(xr[i][0], xr[i][1]);
                #pragma unroll
                for (int nt = 0; nt < 4; ++nt)
                    acc[i][nt] = MFMA16(a, winfrag[nt], acc[i][nt]);
            }
        }

        // ---- recurrent term ----
        if (t > 0) {
            const _Float16* sprev = (t & 1) ? sbuf0 : sbuf1;
            const unsigned target = (unsigned)t;   // flag >= t <=> s[t-1] published

            const bool fast = (t >= 2) && (fast_sh != 0);   // block-uniform
            if (fast) {
                unsigned* mw = &mask2[t & 1];
                if (wave == 0) {
                    // sole global poller; relays partial readiness via LDS.
                    // wave0 itself exits only at the full mask (it carries the
                    // relay duty); its own bits are 0..3 anyway.
                    unsigned fm = poll32(bandflags, lane, target);
                    if (lane == 0)
                        __hip_atomic_store(mw, fm, __ATOMIC_RELAXED,
                                           __HIP_MEMORY_SCOPE_WORKGROUP);
                    int spins = 0;
                    while (fm != 0xffffffffu) {
                        if (++spins > 16) __builtin_amdgcn_s_sleep(1);
                        fm = poll32(bandflags, lane, target);
                        if (lane == 0)
                            __hip_atomic_store(mw, fm, __ATOMIC_RELAXED,
                                               __HIP_MEMORY_SCOPE_WORKGROUP);
                    }
                } else {
                    // local LDS spin: proceed when MY 4 producers are ready
                    unsigned m;
                    int spins = 0;
                    do {
                        m = __hip_atomic_load(mw, __ATOMIC_RELAXED,
                                              __HIP_MEMORY_SCOPE_WORKGROUP);
                        if (++spins > 200) __builtin_amdgcn_s_sleep(1);
                    } while ((m & req) != req);
                }
                // per-wave L1 invalidate, then r17's plain dwordx4 loads
                asm volatile("buffer_inv sc0" ::: "memory");
            } else {
                // r17 centralized safe path (t==1, or non-co-located band)
                if (wave == 0) {
                    unsigned fm = poll32(bandflags, lane, target);
                    int spins = 0;
                    while (fm != 0xffffffffu) {
                        if (++spins > 16) __builtin_amdgcn_s_sleep(1);
                        fm = poll32(bandflags, lane, target);
                    }
                    if (t == 1) {
                        // one-time: verify XCD co-location (xcds visible: flag>=1)
                        const unsigned myx = get_xcc_id() + 1u;
                        unsigned px = __hip_atomic_load(bandxcc + (lane & 31),
                                                        __ATOMIC_RELAXED,
                                                        __HIP_MEMORY_SCOPE_AGENT);
                        unsigned fw = (__ballot(px == myx) == ~0ull) ? 1u : 0u;
                        if (lane == 0) fast_sh = (int)fw;
                    }
                    // safe: full agent acquire (L1+L2 invalidate)
                    __builtin_amdgcn_fence(__ATOMIC_ACQUIRE, "agent");
                }
                __syncthreads();                   // barrier 1 (safe path only)
                asm volatile("" ::: "memory");
            }

            const _Float16* fp = sprev + fbase;
            f16x8 af[16];   // all 16 fragments: flat issue, max MLP (r17 path)

            #pragma unroll
            for (int j = 0; j < 8; ++j)
                #pragma unroll
                for (int i = 0; i < 2; ++i)
                    af[j * 2 + i] = *(const f16x8*)(fp + (size_t)i * 32768
                                                    + (size_t)j * 512);
            #pragma unroll
            for (int j = 0; j < 8; ++j) {
                #pragma unroll
                for (int i = 0; i < 2; ++i) {
                    f16x8 av = af[j * 2 + i];
                    acc[i][0] = MFMA16(av, wfrag[0][j], acc[i][0]);
                    acc[i][1] = MFMA16(av, wfrag[1][j], acc[i][1]);
                    acc[i][2] = MFMA16(av, wfrag[2][j], acc[i][2]);
                    acc[i][3] = MFMA16(av, wfrag[3][j], acc[i][3]);
                }
            }
        }

        // ---- reduce 8 k-phase partials through LDS, tanh, swizzled store ----
        #pragma unroll
        for (int i = 0; i < 2; ++i)
            #pragma unroll
            for (int nt = 0; nt < 4; ++nt)
                #pragma unroll
                for (int r = 0; r < 4; ++r)
                    pf[q * BM * PFS + (i * 16 + quad * 4 + r) * PFS + nt * 16 + l16]
                        = acc[i][nt][r];
        __syncthreads();                           // barrier 2 (pf)
        // reset the relay word this parity will use two steps ahead
        // (ordered: after B2(t), before B3(t); next writer passes B3(t) first)
        if (tid == 0 && t < kT - 1) mask2[(t + 1) & 1] = 0;

        f32x4 vs = {};
        #pragma unroll
        for (int p = 0; p < 8; ++p) {
            f32x4 v = *(const f32x4*)&pf[p * BM * PFS + m_loc * PFS + nn];
            vs[0] += v[0]; vs[1] += v[1]; vs[2] += v[2]; vs[3] += v[3];
        }
        float o0 = fast_tanh(vs[0]);
        float o1 = fast_tanh(vs[1]);
        float o2 = fast_tanh(vs[2]);
        float o3 = fast_tanh(vs[3]);

        if (t < kT - 1) {
            _Float16* sout = (t & 1) ? sbuf1 : sbuf0;
            union { u64 u; _Float16 h[4]; } pk;
            pk.h[0] = (_Float16)o0; pk.h[1] = (_Float16)o1;
            pk.h[2] = (_Float16)o2; pk.h[3] = (_Float16)o3;
            u64* dst = (u64*)(sout + soff);        // contiguous across tids
            if (fast_sh) {
                *dst = pk.u;                     // write-back: lands in the
                asm volatile("" ::: "memory");   // XCD's shared L2 (verified)
            } else {
                __hip_atomic_store(dst, pk.u, __ATOMIC_RELAXED,
                                   __HIP_MEMORY_SCOPE_AGENT);  // through to L3
            }
            __builtin_amdgcn_s_waitcnt(0);   // store (and xcc publish) completed
            __syncthreads();                 // barrier 3 (drain; guards pf)
            if (tid == 0)
                __hip_atomic_store(&bandflags[nb], (unsigned)(t + 1),
                                   __ATOMIC_RELAXED, __HIP_MEMORY_SCOPE_AGENT);
        } else {
            // final step: write plain [B, R] fp32 output
            float4 o; o.x = o0; o.y = o1; o.z = o2; o.w = o3;
            *(float4*)(out + (size_t)(m0 + m_loc) * kR + n0 + nn) = o;
        }
    }
}

extern "C" void kernel_launch(void* const* d_in, const int* in_sizes, int n_in,
                              void* d_out, int out_size, void* d_ws, size_t ws_size,
                              hipStream_t stream)
{
    const float* X   = (const float*)d_in[0];  // [B, T, IN]
    const float* Win = (const float*)d_in[1];  // [R, IN]
    const float* W   = (const float*)d_in[2];  // [R, R]
    float* out = (float*)d_out;                // [B, R]

    char* ws = (char*)d_ws;
    _Float16* s0 = (_Float16*)ws;                                  // 1 MB (swizzled)
    _Float16* s1 = (_Float16*)(ws + (size_t)kB * kR * 2);          // 1 MB (swizzled)
    unsigned* flags = (unsigned*)(ws + 2 * (size_t)kB * kR * 2);   // [8][32]
    unsigned* xcds  = flags + kBands * kNB;                        // [8][32]

    hipMemsetAsync(flags, 0, 2 * kBands * kNB * sizeof(unsigned), stream);
    esn_persist<<<kBlocks, 512, 0, stream>>>(X, Win, W, out, s0, s1, flags, xcds);
}

// Round 6
// 2115.721 us; speedup vs baseline: 1.2658x; 1.0218x over previous
//
#include <hip/hip_runtime.h>
#include <hip/hip_fp16.h>
#include <cmath>

// Problem constants (reference: B=256, T=512, IN=64, R=2048)
constexpr int kB  = 256;
constexpr int kT  = 512;
constexpr int kIN = 64;
constexpr int kR  = 2048;

constexpr int kBands  = 8;             // m-bands; band = blockIdx&7 -> XCD-local under
                                       // round-robin dispatch (r9/r12-verified)
constexpr int kNB     = 32;            // n-blocks per band
constexpr int kBlocks = kBands * kNB;  // 256 -> 1 block/CU (r10: 2/CU regresses)
constexpr int BM = 32;                 // batches per block
constexpr int BN = 64;                 // n per block (W-band in registers)
constexpr int PFS = 68;                // partial-scratch row stride (words)

typedef _Float16 f16x8 __attribute__((ext_vector_type(8)));
typedef float    f32x4 __attribute__((ext_vector_type(4)));
typedef unsigned long long u64;

#define MFMA16(a, b, c) __builtin_amdgcn_mfma_f32_16x16x32_f16((a), (b), (c), 0, 0, 0)

__device__ __forceinline__ f16x8 cvt8(float4 a, float4 b) {
    f16x8 v;
    v[0] = (_Float16)a.x; v[1] = (_Float16)a.y; v[2] = (_Float16)a.z; v[3] = (_Float16)a.w;
    v[4] = (_Float16)b.x; v[5] = (_Float16)b.y; v[6] = (_Float16)b.z; v[7] = (_Float16)b.w;
    return v;
}

__device__ __forceinline__ unsigned get_xcc_id() {
    unsigned x;
    asm volatile("s_getreg_b32 %0, hwreg(HW_REG_XCC_ID, 0, 8)" : "=s"(x));
    return x & 0xfu;
}

// Fast tanh: 1 - 2/(e^{2x}+1) via hw v_exp_f32. Saturates exactly to +/-1 for
// large |x|; ~1e-6 abs error — negligible vs the 9.8e-3 f16-path absmax.
__device__ __forceinline__ float fast_tanh(float x) {
    float e = __expf(2.0f * x);
    return 1.0f - 2.0f / (e + 1.0f);
}

// Agent-scope poll (goes to the coherence point / LLC): safe-path only.
__device__ __forceinline__ unsigned poll32(const unsigned* f, int lane, unsigned target) {
    unsigned v = __hip_atomic_load(f + (lane & 31), __ATOMIC_RELAXED, __HIP_MEMORY_SCOPE_AGENT);
    return (unsigned)__ballot(v >= target);
}

// XCD-local poll: sc0 load bypasses L1 and is served by the XCD's shared L2
// (~200 cy vs the agent/LLC round trip). Valid ONLY when the whole band is
// co-located on one XCD (fast_sh) and producers publish with plain
// write-through stores (which land in the same L2) — the identical coherence
// argument the r12-verified DATA fast path already rests on.
__device__ __forceinline__ unsigned poll32_sc0(const unsigned* f, int lane, unsigned target) {
    unsigned v;
    const unsigned* p = f + (lane & 31);
    asm volatile("global_load_dword %0, %1, off sc0\n\t"
                 "s_waitcnt vmcnt(0)"
                 : "=v"(v) : "v"(p) : "memory");
    return (unsigned)__ballot(v >= target);
}

// Persistent ESN, r22 = r17 VERBATIM (r18-r21 all regressed: per-wave poll
// fan-out -28%, publish restructure -5%, bypass-narrow loads -46%, LDS-relay
// partial-start -15% — steady-state is lockstep, sync topology is locally
// optimal) + ONE lever: cheap flag TRANSPORT on the fast path.
//   Theory: __hip_atomic_* at AGENT scope sets the L2-bypass bit, so every
//   flag publish writes through to the LLC and every poll is an LLC round
//   trip (~600-900 cy); 2-4 retries/step ~ 1 us of pure transport latency on
//   the serial cycle. The band is XCD-co-located (fast_sh, verified t==1),
//   so flags only need XCD scope:
//   - publish: plain volatile store (write-through L1 -> XCD L2)
//   - poll:    global_load_dword sc0 (L1-bypass, served by XCD L2)
//   Producer and consumer branch on the same per-band fast_sh, so scopes
//   always match. Slow path + t==1 keep agent semantics verbatim.
__global__ __launch_bounds__(512, 2) void esn_persist(
    const float* __restrict__ X,     // [B, T, IN]
    const float* __restrict__ Win,   // [R, IN]
    const float* __restrict__ W,     // [R, R]
    float* __restrict__ out,         // [B, R]
    _Float16* __restrict__ sbuf0,    // swizzled, 1 MB
    _Float16* __restrict__ sbuf1,    // swizzled, 1 MB
    unsigned* __restrict__ flags,    // [8][32], zeroed at launch
    unsigned* __restrict__ xcds)     // [8][32], zeroed at launch
{
    __shared__ __align__(16) float pf[8 * BM * PFS];     // 69632 B
    __shared__ int fast_sh;

    const int tid  = threadIdx.x;
    const int wave = tid >> 6, lane = tid & 63;
    const int quad = lane >> 4, l16 = lane & 15;
    const int q  = wave;             // k-phase: k-slab [256q, 256q+256)
    const int mb = blockIdx.x & 7;   // band (XCD-local heuristic, HW-verified)
    const int nb = blockIdx.x >> 3;  // n-block within band
    const int n0 = nb * BN;
    const int m0 = mb * BM;
    unsigned* bandflags = flags + mb * kNB;
    unsigned* bandxcc   = xcds  + mb * kNB;

    if (tid == 0) {
        fast_sh = 0;
        __hip_atomic_store(&bandxcc[nb], get_xcc_id() + 1u,
                           __ATOMIC_RELAXED, __HIP_MEMORY_SCOPE_AGENT);
    }

    // ---- one-time: W-band -> register B-frags (f16) ----
    // wfrag[nt][j] = W[n0+nt*16+l16][kk*32+quad*8+..], kk = 8q+j, j=0..7
    f16x8 wfrag[4][8];
    #pragma unroll
    for (int nt = 0; nt < 4; ++nt) {
        const float* wrow = W + (size_t)(n0 + nt * 16 + l16) * kR;
        #pragma unroll
        for (int j = 0; j < 8; ++j) {
            const float* p = wrow + (8 * q + j) * 32 + quad * 8;
            wfrag[nt][j] = cvt8(*(const float4*)p, *(const float4*)(p + 4));
        }
    }
    // input term: K=64 = 2 k-windows; waves q=0,1 own window q
    f16x8 winfrag[4] = {};
    if (q < 2) {
        #pragma unroll
        for (int nt = 0; nt < 4; ++nt) {
            const float* p = Win + (size_t)(n0 + nt * 16 + l16) * kIN
                           + q * 32 + quad * 8;
            winfrag[nt] = cvt8(*(const float4*)p, *(const float4*)(p + 4));
        }
    }

    // Consumer fragment geometry (swizzled layout, r15-verified):
    // frag (mt, j) at halfs offset fbase + mt*32768 + j*512, kw = 8q+j.
    const size_t fbase = ((size_t)(mb * 2) * 64 + 8 * q) * 512 + quad * 128 + l16 * 8;

    // Producer epilogue geometry (r15-verified): 4 contiguous 1-KB runs.
    const int r_   = tid >> 7;            // run 0..3
    const int pos  = (tid & 127) * 4;     // halfs within run
    const int mt_w = r_ >> 1, kwl = r_ & 1;
    const int l16w = (pos >> 3) & 15, qw = pos >> 7, jw = pos & 7;
    const int m_loc = mt_w * 16 + l16w;                 // m within band
    const int nn    = kwl * 32 + qw * 8 + jw;           // n within block (0..63)
    const size_t soff = ((size_t)(mb * 2 + mt_w) * 64 + (nb * 2 + kwl)) * 512 + pos;

    unsigned fastw = 0;   // wave0's register copy of the fast-path predicate

    #pragma unroll 1
    for (int t = 0; t < kT; ++t) {
        // ---- X-frag raw loads for THIS step (latency hidden under sync) ----
        float4 xr[2][2];
        if (q < 2) {
            #pragma unroll
            for (int i = 0; i < 2; ++i) {
                const float* xp = X + ((size_t)(m0 + i * 16 + l16) * kT + t) * kIN
                                + q * 32 + quad * 8;
                xr[i][0] = *(const float4*)xp;
                xr[i][1] = *(const float4*)(xp + 4);
            }
        }

        f32x4 acc[2][4] = {};   // [m-tile][n-tile]

        // ---- recurrent term: disjoint swizzled fragment loads, flat issue ----
        if (t > 0) {
            const _Float16* sprev = (t & 1) ? sbuf0 : sbuf1;
            const unsigned target = (unsigned)t;   // flag >= t <=> s[t-1] published

            if (wave == 0) {
                // whole-band detect; hot-spin first, sleep only if straggling.
                // fast path: sc0 polls (XCD L2, ~200cy) instead of agent/LLC.
                unsigned fm;
                if (fastw && t >= 2) {
                    fm = poll32_sc0(bandflags, lane, target);
                    int spins = 0;
                    while (fm != 0xffffffffu) {
                        if (++spins > 16) __builtin_amdgcn_s_sleep(1);
                        fm = poll32_sc0(bandflags, lane, target);
                    }
                } else {
                    fm = poll32(bandflags, lane, target);
                    int spins = 0;
                    while (fm != 0xffffffffu) {
                        if (++spins > 16) __builtin_amdgcn_s_sleep(1);
                        fm = poll32(bandflags, lane, target);
                    }
                }
                if (t == 1) {
                    // one-time: verify XCD co-location (xcds visible: flag>=1)
                    const unsigned myx = get_xcc_id() + 1u;
                    unsigned px = __hip_atomic_load(bandxcc + (lane & 31),
                                                    __ATOMIC_RELAXED,
                                                    __HIP_MEMORY_SCOPE_AGENT);
                    fastw = (__ballot(px == myx) == ~0ull) ? 1u : 0u;
                    if (lane == 0) fast_sh = (int)fastw;
                }
                if (fastw && t >= 2) {
                    // fast: L1-only invalidate (per-CU, parallel); s lives in
                    // this XCD's shared L2, updated directly by peers' stores.
                    asm volatile("buffer_inv sc0" ::: "memory");
                } else {
                    // safe: full agent acquire (L1+L2 invalidate)
                    __builtin_amdgcn_fence(__ATOMIC_ACQUIRE, "agent");
                }
            }
            __syncthreads();                       // barrier 1 (detect/inv)
            asm volatile("" ::: "memory");

            const _Float16* fp = sprev + fbase;
            f16x8 af[16];   // all 16 fragments: flat issue, max MLP

            #pragma unroll
            for (int j = 0; j < 8; ++j)
                #pragma unroll
                for (int i = 0; i < 2; ++i)
                    af[j * 2 + i] = *(const f16x8*)(fp + (size_t)i * 32768
                                                    + (size_t)j * 512);
            #pragma unroll
            for (int j = 0; j < 8; ++j) {
                #pragma unroll
                for (int i = 0; i < 2; ++i) {
                    f16x8 av = af[j * 2 + i];
                    acc[i][0] = MFMA16(av, wfrag[0][j], acc[i][0]);
                    acc[i][1] = MFMA16(av, wfrag[1][j], acc[i][1]);
                    acc[i][2] = MFMA16(av, wfrag[2][j], acc[i][2]);
                    acc[i][3] = MFMA16(av, wfrag[3][j], acc[i][3]);
                }
            }
        }

        // ---- input term (X loads long done) ----
        if (q < 2) {
            #pragma unroll
            for (int i = 0; i < 2; ++i) {
                f16x8 a = cvt8(xr[i][0], xr[i][1]);
                #pragma unroll
                for (int nt = 0; nt < 4; ++nt)
                    acc[i][nt] = MFMA16(a, winfrag[nt], acc[i][nt]);
            }
        }

        // ---- reduce 8 k-phase partials through LDS, tanh, swizzled store ----
        #pragma unroll
        for (int i = 0; i < 2; ++i)
            #pragma unroll
            for (int nt = 0; nt < 4; ++nt)
                #pragma unroll
                for (int r = 0; r < 4; ++r)
                    pf[q * BM * PFS + (i * 16 + quad * 4 + r) * PFS + nt * 16 + l16]
                        = acc[i][nt][r];
        __syncthreads();                           // barrier 2 (pf)

        f32x4 vs = {};
        #pragma unroll
        for (int p = 0; p < 8; ++p) {
            f32x4 v = *(const f32x4*)&pf[p * BM * PFS + m_loc * PFS + nn];
            vs[0] += v[0]; vs[1] += v[1]; vs[2] += v[2]; vs[3] += v[3];
        }
        float o0 = fast_tanh(vs[0]);
        float o1 = fast_tanh(vs[1]);
        float o2 = fast_tanh(vs[2]);
        float o3 = fast_tanh(vs[3]);

        if (t < kT - 1) {
            _Float16* sout = (t & 1) ? sbuf1 : sbuf0;
            union { u64 u; _Float16 h[4]; } pk;
            pk.h[0] = (_Float16)o0; pk.h[1] = (_Float16)o1;
            pk.h[2] = (_Float16)o2; pk.h[3] = (_Float16)o3;
            u64* dst = (u64*)(sout + soff);        // contiguous across tids
            if (fast_sh) {
                *dst = pk.u;                     // write-back: lands in the
                asm volatile("" ::: "memory");   // XCD's shared L2 (verified)
            } else {
                __hip_atomic_store(dst, pk.u, __ATOMIC_RELAXED,
                                   __HIP_MEMORY_SCOPE_AGENT);  // through to L3
            }
            __builtin_amdgcn_s_waitcnt(0);   // store (and xcc publish) completed
            __syncthreads();                 // barrier 3 (drain; guards pf)
            if (tid == 0) {
                if (fast_sh) {
                    // XCD-local publish: plain write-through store -> L2;
                    // matches consumers' sc0 polls (same band, same XCD).
                    volatile unsigned* fl = &bandflags[nb];
                    *fl = (unsigned)(t + 1);
                } else {
                    __hip_atomic_store(&bandflags[nb], (unsigned)(t + 1),
                                       __ATOMIC_RELAXED, __HIP_MEMORY_SCOPE_AGENT);
                }
            }
        } else {
            // final step: write plain [B, R] fp32 output
            float4 o; o.x = o0; o.y = o1; o.z = o2; o.w = o3;
            *(float4*)(out + (size_t)(m0 + m_loc) * kR + n0 + nn) = o;
        }
    }
}

extern "C" void kernel_launch(void* const* d_in, const int* in_sizes, int n_in,
                              void* d_out, int out_size, void* d_ws, size_t ws_size,
                              hipStream_t stream)
{
    const float* X   = (const float*)d_in[0];  // [B, T, IN]
    const float* Win = (const float*)d_in[1];  // [R, IN]
    const float* W   = (const float*)d_in[2];  // [R, R]
    float* out = (float*)d_out;                // [B, R]

    char* ws = (char*)d_ws;
    _Float16* s0 = (_Float16*)ws;                                  // 1 MB (swizzled)
    _Float16* s1 = (_Float16*)(ws + (size_t)kB * kR * 2);          // 1 MB (swizzled)
    unsigned* flags = (unsigned*)(ws + 2 * (size_t)kB * kR * 2);   // [8][32]
    unsigned* xcds  = flags + kBands * kNB;                        // [8][32]

    hipMemsetAsync(flags, 0, 2 * kBands * kNB * sizeof(unsigned), stream);
    esn_persist<<<kBlocks, 512, 0, stream>>>(X, Win, W, out, s0, s1, flags, xcds);
}

// Round 7
// 1845.968 us; speedup vs baseline: 1.4507x; 1.1461x over previous
//
#include <hip/hip_runtime.h>
#include <hip/hip_fp16.h>
#include <cmath>

// Problem constants (reference: B=256, T=512, IN=64, R=2048)
constexpr int kB  = 256;
constexpr int kT  = 512;
constexpr int kIN = 64;
constexpr int kR  = 2048;

constexpr int kBands  = 8;             // m-bands; band = blockIdx&7 -> XCD-local under
                                       // round-robin dispatch (r9/r12-verified)
constexpr int kNB     = 32;            // n-blocks per band
constexpr int kBlocks = kBands * kNB;  // 256 -> 1 block/CU (r10: 2/CU regresses)
constexpr int BM = 32;                 // batches per block
constexpr int BN = 64;                 // n per block (W-band in registers)
constexpr int PFS = 68;                // partial-scratch row stride (words)

typedef _Float16 f16x8 __attribute__((ext_vector_type(8)));
typedef float    f32x4 __attribute__((ext_vector_type(4)));
typedef unsigned long long u64;

#define MFMA16(a, b, c) __builtin_amdgcn_mfma_f32_16x16x32_f16((a), (b), (c), 0, 0, 0)

__device__ __forceinline__ f16x8 cvt8(float4 a, float4 b) {
    f16x8 v;
    v[0] = (_Float16)a.x; v[1] = (_Float16)a.y; v[2] = (_Float16)a.z; v[3] = (_Float16)a.w;
    v[4] = (_Float16)b.x; v[5] = (_Float16)b.y; v[6] = (_Float16)b.z; v[7] = (_Float16)b.w;
    return v;
}

__device__ __forceinline__ unsigned get_xcc_id() {
    unsigned x;
    asm volatile("s_getreg_b32 %0, hwreg(HW_REG_XCC_ID, 0, 8)" : "=s"(x));
    return x & 0xfu;
}

// Fast tanh: 1 - 2/(e^{2x}+1) via hw v_exp_f32. Saturates exactly to +/-1 for
// large |x|; ~1e-6 abs error — negligible vs the 9.8e-3 f16-path absmax.
__device__ __forceinline__ float fast_tanh(float x) {
    float e = __expf(2.0f * x);
    return 1.0f - 2.0f / (e + 1.0f);
}

// One coalesced poll of the band's 32 per-block flags (agent-scope).
__device__ __forceinline__ unsigned poll32(const unsigned* f, int lane, unsigned target) {
    unsigned v = __hip_atomic_load(f + (lane & 31), __ATOMIC_RELAXED, __HIP_MEMORY_SCOPE_AGENT);
    return (unsigned)__ballot(v >= target);
}

// Persistent ESN, r23 = r17 VERBATIM (measured 1830.7 us, the session best).
// Experiment ledger — every perturbation of the sync/transport design lost:
//   r18 per-wave global poll fan-out ......... -28% (flag-line spin storm)
//   r19 pf-dbuf + counter publish ............ -5%  (LDS RMW chain > barrier)
//   r20 narrow L1-bypass fragment loads ...... -46% (2x L2 request count)
//   r21 LDS-relay partial-start + 8x inv ..... -15% (skew ~0; inv thrash)
//   r22 sc0 flag poll + volatile publish ..... -15% (serialized poll; agent
//                                                    atomics were L2-served)
// => r17's lockstep topology is the measured local optimum. Structural
// alternatives are walled: BN=128 (halves L2 stream) needs ~256 VGPR for W
// alone; n-split (no pf reduce) needs 64 KB W/wave in regs; W-in-LDS needs
// 256 KB > 160 KB; fp8 state risks absmax through 512 recurrence steps.
// Per-step floor of this topology: publish -> observe -> 4 MB/XCD L2
// broadcast (~0.9 us) -> MFMA -> pf reduce -> drain/publish ~= 3.6 us.
__global__ __launch_bounds__(512, 2) void esn_persist(
    const float* __restrict__ X,     // [B, T, IN]
    const float* __restrict__ Win,   // [R, IN]
    const float* __restrict__ W,     // [R, R]
    float* __restrict__ out,         // [B, R]
    _Float16* __restrict__ sbuf0,    // swizzled, 1 MB
    _Float16* __restrict__ sbuf1,    // swizzled, 1 MB
    unsigned* __restrict__ flags,    // [8][32], zeroed at launch
    unsigned* __restrict__ xcds)     // [8][32], zeroed at launch
{
    __shared__ __align__(16) float pf[8 * BM * PFS];     // 69632 B
    __shared__ int fast_sh;

    const int tid  = threadIdx.x;
    const int wave = tid >> 6, lane = tid & 63;
    const int quad = lane >> 4, l16 = lane & 15;
    const int q  = wave;             // k-phase: k-slab [256q, 256q+256)
    const int mb = blockIdx.x & 7;   // band (XCD-local heuristic, HW-verified)
    const int nb = blockIdx.x >> 3;  // n-block within band
    const int n0 = nb * BN;
    const int m0 = mb * BM;
    unsigned* bandflags = flags + mb * kNB;
    unsigned* bandxcc   = xcds  + mb * kNB;

    if (tid == 0) {
        fast_sh = 0;
        __hip_atomic_store(&bandxcc[nb], get_xcc_id() + 1u,
                           __ATOMIC_RELAXED, __HIP_MEMORY_SCOPE_AGENT);
    }

    // ---- one-time: W-band -> register B-frags (f16) ----
    // wfrag[nt][j] = W[n0+nt*16+l16][kk*32+quad*8+..], kk = 8q+j, j=0..7
    f16x8 wfrag[4][8];
    #pragma unroll
    for (int nt = 0; nt < 4; ++nt) {
        const float* wrow = W + (size_t)(n0 + nt * 16 + l16) * kR;
        #pragma unroll
        for (int j = 0; j < 8; ++j) {
            const float* p = wrow + (8 * q + j) * 32 + quad * 8;
            wfrag[nt][j] = cvt8(*(const float4*)p, *(const float4*)(p + 4));
        }
    }
    // input term: K=64 = 2 k-windows; waves q=0,1 own window q
    f16x8 winfrag[4] = {};
    if (q < 2) {
        #pragma unroll
        for (int nt = 0; nt < 4; ++nt) {
            const float* p = Win + (size_t)(n0 + nt * 16 + l16) * kIN
                           + q * 32 + quad * 8;
            winfrag[nt] = cvt8(*(const float4*)p, *(const float4*)(p + 4));
        }
    }

    // Consumer fragment geometry (swizzled layout, r15-verified):
    // frag (mt, j) at halfs offset fbase + mt*32768 + j*512, kw = 8q+j.
    const size_t fbase = ((size_t)(mb * 2) * 64 + 8 * q) * 512 + quad * 128 + l16 * 8;

    // Producer epilogue geometry (r15-verified): 4 contiguous 1-KB runs.
    const int r_   = tid >> 7;            // run 0..3
    const int pos  = (tid & 127) * 4;     // halfs within run
    const int mt_w = r_ >> 1, kwl = r_ & 1;
    const int l16w = (pos >> 3) & 15, qw = pos >> 7, jw = pos & 7;
    const int m_loc = mt_w * 16 + l16w;                 // m within band
    const int nn    = kwl * 32 + qw * 8 + jw;           // n within block (0..63)
    const size_t soff = ((size_t)(mb * 2 + mt_w) * 64 + (nb * 2 + kwl)) * 512 + pos;

    unsigned fastw = 0;   // wave0's register copy of the fast-path predicate

    #pragma unroll 1
    for (int t = 0; t < kT; ++t) {
        // ---- X-frag raw loads for THIS step (latency hidden under sync) ----
        float4 xr[2][2];
        if (q < 2) {
            #pragma unroll
            for (int i = 0; i < 2; ++i) {
                const float* xp = X + ((size_t)(m0 + i * 16 + l16) * kT + t) * kIN
                                + q * 32 + quad * 8;
                xr[i][0] = *(const float4*)xp;
                xr[i][1] = *(const float4*)(xp + 4);
            }
        }

        f32x4 acc[2][4] = {};   // [m-tile][n-tile]

        // ---- recurrent term: disjoint swizzled fragment loads, flat issue ----
        if (t > 0) {
            const _Float16* sprev = (t & 1) ? sbuf0 : sbuf1;
            const unsigned target = (unsigned)t;   // flag >= t <=> s[t-1] published

            if (wave == 0) {
                // whole-band detect; hot-spin first, sleep only if straggling
                unsigned fm = poll32(bandflags, lane, target);
                int spins = 0;
                while (fm != 0xffffffffu) {
                    if (++spins > 16) __builtin_amdgcn_s_sleep(1);
                    fm = poll32(bandflags, lane, target);
                }
                if (t == 1) {
                    // one-time: verify XCD co-location (xcds visible: flag>=1)
                    const unsigned myx = get_xcc_id() + 1u;
                    unsigned px = __hip_atomic_load(bandxcc + (lane & 31),
                                                    __ATOMIC_RELAXED,
                                                    __HIP_MEMORY_SCOPE_AGENT);
                    fastw = (__ballot(px == myx) == ~0ull) ? 1u : 0u;
                    if (lane == 0) fast_sh = (int)fastw;
                }
                if (fastw && t >= 2) {
                    // fast: L1-only invalidate (per-CU, parallel); s lives in
                    // this XCD's shared L2, updated directly by peers' stores.
                    asm volatile("buffer_inv sc0" ::: "memory");
                } else {
                    // safe: full agent acquire (L1+L2 invalidate)
                    __builtin_amdgcn_fence(__ATOMIC_ACQUIRE, "agent");
                }
            }
            __syncthreads();                       // barrier 1 (detect/inv)
            asm volatile("" ::: "memory");

            const _Float16* fp = sprev + fbase;
            f16x8 af[16];   // all 16 fragments: flat issue, max MLP

            #pragma unroll
            for (int j = 0; j < 8; ++j)
                #pragma unroll
                for (int i = 0; i < 2; ++i)
                    af[j * 2 + i] = *(const f16x8*)(fp + (size_t)i * 32768
                                                    + (size_t)j * 512);
            #pragma unroll
            for (int j = 0; j < 8; ++j) {
                #pragma unroll
                for (int i = 0; i < 2; ++i) {
                    f16x8 av = af[j * 2 + i];
                    acc[i][0] = MFMA16(av, wfrag[0][j], acc[i][0]);
                    acc[i][1] = MFMA16(av, wfrag[1][j], acc[i][1]);
                    acc[i][2] = MFMA16(av, wfrag[2][j], acc[i][2]);
                    acc[i][3] = MFMA16(av, wfrag[3][j], acc[i][3]);
                }
            }
        }

        // ---- input term (X loads long done) ----
        if (q < 2) {
            #pragma unroll
            for (int i = 0; i < 2; ++i) {
                f16x8 a = cvt8(xr[i][0], xr[i][1]);
                #pragma unroll
                for (int nt = 0; nt < 4; ++nt)
                    acc[i][nt] = MFMA16(a, winfrag[nt], acc[i][nt]);
            }
        }

        // ---- reduce 8 k-phase partials through LDS, tanh, swizzled store ----
        #pragma unroll
        for (int i = 0; i < 2; ++i)
            #pragma unroll
            for (int nt = 0; nt < 4; ++nt)
                #pragma unroll
                for (int r = 0; r < 4; ++r)
                    pf[q * BM * PFS + (i * 16 + quad * 4 + r) * PFS + nt * 16 + l16]
                        = acc[i][nt][r];
        __syncthreads();                           // barrier 2 (pf)

        f32x4 vs = {};
        #pragma unroll
        for (int p = 0; p < 8; ++p) {
            f32x4 v = *(const f32x4*)&pf[p * BM * PFS + m_loc * PFS + nn];
            vs[0] += v[0]; vs[1] += v[1]; vs[2] += v[2]; vs[3] += v[3];
        }
        float o0 = fast_tanh(vs[0]);
        float o1 = fast_tanh(vs[1]);
        float o2 = fast_tanh(vs[2]);
        float o3 = fast_tanh(vs[3]);

        if (t < kT - 1) {
            _Float16* sout = (t & 1) ? sbuf1 : sbuf0;
            union { u64 u; _Float16 h[4]; } pk;
            pk.h[0] = (_Float16)o0; pk.h[1] = (_Float16)o1;
            pk.h[2] = (_Float16)o2; pk.h[3] = (_Float16)o3;
            u64* dst = (u64*)(sout + soff);        // contiguous across tids
            if (fast_sh) {
                *dst = pk.u;                     // write-back: lands in the
                asm volatile("" ::: "memory");   // XCD's shared L2 (verified)
            } else {
                __hip_atomic_store(dst, pk.u, __ATOMIC_RELAXED,
                                   __HIP_MEMORY_SCOPE_AGENT);  // through to L3
            }
            __builtin_amdgcn_s_waitcnt(0);   // store (and xcc publish) completed
            __syncthreads();                 // barrier 3 (drain; guards pf)
            if (tid == 0)
                __hip_atomic_store(&bandflags[nb], (unsigned)(t + 1),
                                   __ATOMIC_RELAXED, __HIP_MEMORY_SCOPE_AGENT);
        } else {
            // final step: write plain [B, R] fp32 output
            float4 o; o.x = o0; o.y = o1; o.z = o2; o.w = o3;
            *(float4*)(out + (size_t)(m0 + m_loc) * kR + n0 + nn) = o;
        }
    }
}

extern "C" void kernel_launch(void* const* d_in, const int* in_sizes, int n_in,
                              void* d_out, int out_size, void* d_ws, size_t ws_size,
                              hipStream_t stream)
{
    const float* X   = (const float*)d_in[0];  // [B, T, IN]
    const float* Win = (const float*)d_in[1];  // [R, IN]
    const float* W   = (const float*)d_in[2];  // [R, R]
    float* out = (float*)d_out;                // [B, R]

    char* ws = (char*)d_ws;
    _Float16* s0 = (_Float16*)ws;                                  // 1 MB (swizzled)
    _Float16* s1 = (_Float16*)(ws + (size_t)kB * kR * 2);          // 1 MB (swizzled)
    unsigned* flags = (unsigned*)(ws + 2 * (size_t)kB * kR * 2);   // [8][32]
    unsigned* xcds  = flags + kBands * kNB;                        // [8][32]

    hipMemsetAsync(flags, 0, 2 * kBands * kNB * sizeof(unsigned), stream);
    esn_persist<<<kBlocks, 512, 0, stream>>>(X, Win, W, out, s0, s1, flags, xcds);
}

// Round 8
// 1753.636 us; speedup vs baseline: 1.5271x; 1.0527x over previous
//
#include <hip/hip_runtime.h>
#include <hip/hip_fp16.h>
#include <cmath>

// Problem constants (reference: B=256, T=512, IN=64, R=2048)
constexpr int kB  = 256;
constexpr int kT  = 512;
constexpr int kIN = 64;
constexpr int kR  = 2048;

constexpr int kBands  = 8;             // m-bands; band = blockIdx&7 -> XCD-local under
                                       // round-robin dispatch (r9/r12-verified)
constexpr int kNB     = 32;            // n-blocks per band
constexpr int kBlocks = kBands * kNB;  // 256 -> 1 block/CU (r10: 2/CU regresses)
constexpr int BM = 32;                 // batches per block
constexpr int BN = 64;                 // n per block (W-band in registers)
constexpr int PFS = 68;                // partial-scratch row stride (words)

typedef _Float16 f16x8 __attribute__((ext_vector_type(8)));
typedef float    f32x4 __attribute__((ext_vector_type(4)));
typedef unsigned long long u64;

#define MFMA16(a, b, c) __builtin_amdgcn_mfma_f32_16x16x32_f16((a), (b), (c), 0, 0, 0)

__device__ __forceinline__ f16x8 cvt8(float4 a, float4 b) {
    f16x8 v;
    v[0] = (_Float16)a.x; v[1] = (_Float16)a.y; v[2] = (_Float16)a.z; v[3] = (_Float16)a.w;
    v[4] = (_Float16)b.x; v[5] = (_Float16)b.y; v[6] = (_Float16)b.z; v[7] = (_Float16)b.w;
    return v;
}

__device__ __forceinline__ unsigned get_xcc_id() {
    unsigned x;
    asm volatile("s_getreg_b32 %0, hwreg(HW_REG_XCC_ID, 0, 8)" : "=s"(x));
    return x & 0xfu;
}

// Fast tanh: 1 - 2/(e^{2x}+1) via hw v_exp_f32. Saturates exactly to +/-1 for
// large |x|; ~1e-6 abs error — negligible vs the 9.8e-3 f16-path absmax.
__device__ __forceinline__ float fast_tanh(float x) {
    float e = __expf(2.0f * x);
    return 1.0f - 2.0f / (e + 1.0f);
}

// One coalesced poll of the band's 32 per-block flags (agent-scope).
__device__ __forceinline__ unsigned poll32(const unsigned* f, int lane, unsigned target) {
    unsigned v = __hip_atomic_load(f + (lane & 31), __ATOMIC_RELAXED, __HIP_MEMORY_SCOPE_AGENT);
    return (unsigned)__ballot(v >= target);
}

// Persistent ESN, r24 = r17/r23 (session best, reproduced 1846 us) + ONE
// address-stream lever: per-block k-window ROTATION of the broadcast.
//   Observation: fbase depends only on (mb, q) — all 32 blocks of a band
//   read the IDENTICAL 128-KB address sequence in the IDENTICAL order, and
//   the lockstep flag release fires them simultaneously. 32 CUs hitting the
//   same L2 line at the same instant serialize on that line's port; the
//   whole band then marches to the next line together. This phase-aligned
//   storm can run the stream far below the ~4.3 TB/s/XCD aggregate figure
//   and would explain the ~1.5 us/step of unexplained stream time.
//   Fix: block nb starts its k-window walk at jrot = nb&7. BOTH wfrag init
//   and the fragment-load offsets rotate by jrot, so the af<->wfrag pairing
//   stays static (no runtime-indexed register arrays) and the j-accumulation
//   is merely reordered (fp32 reassociation only). Sync topology, publish,
//   epilogue: verbatim r17 (r18-r22 ledger: all perturbations there lost).
__global__ __launch_bounds__(512, 2) void esn_persist(
    const float* __restrict__ X,     // [B, T, IN]
    const float* __restrict__ Win,   // [R, IN]
    const float* __restrict__ W,     // [R, R]
    float* __restrict__ out,         // [B, R]
    _Float16* __restrict__ sbuf0,    // swizzled, 1 MB
    _Float16* __restrict__ sbuf1,    // swizzled, 1 MB
    unsigned* __restrict__ flags,    // [8][32], zeroed at launch
    unsigned* __restrict__ xcds)     // [8][32], zeroed at launch
{
    __shared__ __align__(16) float pf[8 * BM * PFS];     // 69632 B
    __shared__ int fast_sh;

    const int tid  = threadIdx.x;
    const int wave = tid >> 6, lane = tid & 63;
    const int quad = lane >> 4, l16 = lane & 15;
    const int q  = wave;             // k-phase: k-slab [256q, 256q+256)
    const int mb = blockIdx.x & 7;   // band (XCD-local heuristic, HW-verified)
    const int nb = blockIdx.x >> 3;  // n-block within band
    const int n0 = nb * BN;
    const int m0 = mb * BM;
    const int jrot = nb & 7;         // per-block k-window phase (r24)
    unsigned* bandflags = flags + mb * kNB;
    unsigned* bandxcc   = xcds  + mb * kNB;

    if (tid == 0) {
        fast_sh = 0;
        __hip_atomic_store(&bandxcc[nb], get_xcc_id() + 1u,
                           __ATOMIC_RELAXED, __HIP_MEMORY_SCOPE_AGENT);
    }

    // ---- one-time: W-band -> register B-frags (f16), jrot-rotated ----
    // wfrag[nt][jj] = W[n0+nt*16+l16][kk*32+quad*8+..], kk = 8q + (jj+jrot)&7
    f16x8 wfrag[4][8];
    #pragma unroll
    for (int nt = 0; nt < 4; ++nt) {
        const float* wrow = W + (size_t)(n0 + nt * 16 + l16) * kR;
        #pragma unroll
        for (int jj = 0; jj < 8; ++jj) {
            const int jw = (jj + jrot) & 7;
            const float* p = wrow + (8 * q + jw) * 32 + quad * 8;
            wfrag[nt][jj] = cvt8(*(const float4*)p, *(const float4*)(p + 4));
        }
    }
    // input term: K=64 = 2 k-windows; waves q=0,1 own window q
    f16x8 winfrag[4] = {};
    if (q < 2) {
        #pragma unroll
        for (int nt = 0; nt < 4; ++nt) {
            const float* p = Win + (size_t)(n0 + nt * 16 + l16) * kIN
                           + q * 32 + quad * 8;
            winfrag[nt] = cvt8(*(const float4*)p, *(const float4*)(p + 4));
        }
    }

    // Consumer fragment geometry (swizzled layout, r15-verified):
    // frag (mt, jj) at halfs offset fbase + mt*32768 + ((jj+jrot)&7)*512.
    const size_t fbase = ((size_t)(mb * 2) * 64 + 8 * q) * 512 + quad * 128 + l16 * 8;

    // Producer epilogue geometry (r15-verified): 4 contiguous 1-KB runs.
    const int r_   = tid >> 7;            // run 0..3
    const int pos  = (tid & 127) * 4;     // halfs within run
    const int mt_w = r_ >> 1, kwl = r_ & 1;
    const int l16w = (pos >> 3) & 15, qw = pos >> 7, jw_ = pos & 7;
    const int m_loc = mt_w * 16 + l16w;                 // m within band
    const int nn    = kwl * 32 + qw * 8 + jw_;          // n within block (0..63)
    const size_t soff = ((size_t)(mb * 2 + mt_w) * 64 + (nb * 2 + kwl)) * 512 + pos;

    unsigned fastw = 0;   // wave0's register copy of the fast-path predicate

    #pragma unroll 1
    for (int t = 0; t < kT; ++t) {
        // ---- X-frag raw loads for THIS step (latency hidden under sync) ----
        float4 xr[2][2];
        if (q < 2) {
            #pragma unroll
            for (int i = 0; i < 2; ++i) {
                const float* xp = X + ((size_t)(m0 + i * 16 + l16) * kT + t) * kIN
                                + q * 32 + quad * 8;
                xr[i][0] = *(const float4*)xp;
                xr[i][1] = *(const float4*)(xp + 4);
            }
        }

        f32x4 acc[2][4] = {};   // [m-tile][n-tile]

        // ---- recurrent term: disjoint swizzled fragment loads, flat issue ----
        if (t > 0) {
            const _Float16* sprev = (t & 1) ? sbuf0 : sbuf1;
            const unsigned target = (unsigned)t;   // flag >= t <=> s[t-1] published

            if (wave == 0) {
                // whole-band detect; hot-spin first, sleep only if straggling
                unsigned fm = poll32(bandflags, lane, target);
                int spins = 0;
                while (fm != 0xffffffffu) {
                    if (++spins > 16) __builtin_amdgcn_s_sleep(1);
                    fm = poll32(bandflags, lane, target);
                }
                if (t == 1) {
                    // one-time: verify XCD co-location (xcds visible: flag>=1)
                    const unsigned myx = get_xcc_id() + 1u;
                    unsigned px = __hip_atomic_load(bandxcc + (lane & 31),
                                                    __ATOMIC_RELAXED,
                                                    __HIP_MEMORY_SCOPE_AGENT);
                    fastw = (__ballot(px == myx) == ~0ull) ? 1u : 0u;
                    if (lane == 0) fast_sh = (int)fastw;
                }
                if (fastw && t >= 2) {
                    // fast: L1-only invalidate (per-CU, parallel); s lives in
                    // this XCD's shared L2, updated directly by peers' stores.
                    asm volatile("buffer_inv sc0" ::: "memory");
                } else {
                    // safe: full agent acquire (L1+L2 invalidate)
                    __builtin_amdgcn_fence(__ATOMIC_ACQUIRE, "agent");
                }
            }
            __syncthreads();                       // barrier 1 (detect/inv)
            asm volatile("" ::: "memory");

            const _Float16* fp = sprev + fbase;
            f16x8 af[16];   // all 16 fragments: flat issue, max MLP
                            // (af index jj is STATIC; rotation lives in the
                            //  address and in wfrag's init-time pairing)

            #pragma unroll
            for (int jj = 0; jj < 8; ++jj)
                #pragma unroll
                for (int i = 0; i < 2; ++i)
                    af[jj * 2 + i] = *(const f16x8*)(fp + (size_t)i * 32768
                                                     + (size_t)((jj + jrot) & 7) * 512);
            #pragma unroll
            for (int jj = 0; jj < 8; ++jj) {
                #pragma unroll
                for (int i = 0; i < 2; ++i) {
                    f16x8 av = af[jj * 2 + i];
                    acc[i][0] = MFMA16(av, wfrag[0][jj], acc[i][0]);
                    acc[i][1] = MFMA16(av, wfrag[1][jj], acc[i][1]);
                    acc[i][2] = MFMA16(av, wfrag[2][jj], acc[i][2]);
                    acc[i][3] = MFMA16(av, wfrag[3][jj], acc[i][3]);
                }
            }
        }

        // ---- input term (X loads long done) ----
        if (q < 2) {
            #pragma unroll
            for (int i = 0; i < 2; ++i) {
                f16x8 a = cvt8(xr[i][0], xr[i][1]);
                #pragma unroll
                for (int nt = 0; nt < 4; ++nt)
                    acc[i][nt] = MFMA16(a, winfrag[nt], acc[i][nt]);
            }
        }

        // ---- reduce 8 k-phase partials through LDS, tanh, swizzled store ----
        #pragma unroll
        for (int i = 0; i < 2; ++i)
            #pragma unroll
            for (int nt = 0; nt < 4; ++nt)
                #pragma unroll
                for (int r = 0; r < 4; ++r)
                    pf[q * BM * PFS + (i * 16 + quad * 4 + r) * PFS + nt * 16 + l16]
                        = acc[i][nt][r];
        __syncthreads();                           // barrier 2 (pf)

        f32x4 vs = {};
        #pragma unroll
        for (int p = 0; p < 8; ++p) {
            f32x4 v = *(const f32x4*)&pf[p * BM * PFS + m_loc * PFS + nn];
            vs[0] += v[0]; vs[1] += v[1]; vs[2] += v[2]; vs[3] += v[3];
        }
        float o0 = fast_tanh(vs[0]);
        float o1 = fast_tanh(vs[1]);
        float o2 = fast_tanh(vs[2]);
        float o3 = fast_tanh(vs[3]);

        if (t < kT - 1) {
            _Float16* sout = (t & 1) ? sbuf1 : sbuf0;
            union { u64 u; _Float16 h[4]; } pk;
            pk.h[0] = (_Float16)o0; pk.h[1] = (_Float16)o1;
            pk.h[2] = (_Float16)o2; pk.h[3] = (_Float16)o3;
            u64* dst = (u64*)(sout + soff);        // contiguous across tids
            if (fast_sh) {
                *dst = pk.u;                     // write-back: lands in the
                asm volatile("" ::: "memory");   // XCD's shared L2 (verified)
            } else {
                __hip_atomic_store(dst, pk.u, __ATOMIC_RELAXED,
                                   __HIP_MEMORY_SCOPE_AGENT);  // through to L3
            }
            __builtin_amdgcn_s_waitcnt(0);   // store (and xcc publish) completed
            __syncthreads();                 // barrier 3 (drain; guards pf)
            if (tid == 0)
                __hip_atomic_store(&bandflags[nb], (unsigned)(t + 1),
                                   __ATOMIC_RELAXED, __HIP_MEMORY_SCOPE_AGENT);
        } else {
            // final step: write plain [B, R] fp32 output
            float4 o; o.x = o0; o.y = o1; o.z = o2; o.w = o3;
            *(float4*)(out + (size_t)(m0 + m_loc) * kR + n0 + nn) = o;
        }
    }
}

extern "C" void kernel_launch(void* const* d_in, const int* in_sizes, int n_in,
                              void* d_out, int out_size, void* d_ws, size_t ws_size,
                              hipStream_t stream)
{
    const float* X   = (const float*)d_in[0];  // [B, T, IN]
    const float* Win = (const float*)d_in[1];  // [R, IN]
    const float* W   = (const float*)d_in[2];  // [R, R]
    float* out = (float*)d_out;                // [B, R]

    char* ws = (char*)d_ws;
    _Float16* s0 = (_Float16*)ws;                                  // 1 MB (swizzled)
    _Float16* s1 = (_Float16*)(ws + (size_t)kB * kR * 2);          // 1 MB (swizzled)
    unsigned* flags = (unsigned*)(ws + 2 * (size_t)kB * kR * 2);   // [8][32]
    unsigned* xcds  = flags + kBands * kNB;                        // [8][32]

    hipMemsetAsync(flags, 0, 2 * kBands * kNB * sizeof(unsigned), stream);
    esn_persist<<<kBlocks, 512, 0, stream>>>(X, Win, W, out, s0, s1, flags, xcds);
}